// Round 1
// baseline (1033.329 us; speedup 1.0000x reference)
//
#include <hip/hip_runtime.h>
#include <hip/hip_bf16.h>
#include <math.h>

#define MIN_POINTS 4

// ---- workspace layout (bytes) ----
#define WS_ST0   0        // 16 doubles (9 used): sx0..2, g00,g01,g02,g11,g12,g22
#define WS_ST1   128      // 128 doubles: sum[64], sumsq[64]
#define WS_W0P   1280     // 192 floats (folded W0')
#define WS_B0P   2048     // 64 floats
#define WS_W1P   2304     // 4096 floats (folded W1')
#define WS_B1P   18688    // 64 floats
#define WS_CNT   18944    // V ints

__device__ __forceinline__ void waitlgkm(){ asm volatile("s_waitcnt lgkmcnt(0)" ::: "memory"); }

// ---------------- K1: global stats of x (3-dim) + vertex counts ----------------
__global__ void k_stats0(const float4* __restrict__ d4, const int* __restrict__ idx,
                         double* __restrict__ st0, int* __restrict__ cnt, int N){
  int tid = blockIdx.x*blockDim.x + threadIdx.x;
  int stride = gridDim.x*blockDim.x;
  double a[9] = {0,0,0,0,0,0,0,0,0};
  for (int i = tid; i < N; i += stride){
    float4 d = d4[i];
    double x0 = d.x, x1 = d.y, x2 = d.z;
    a[0] += x0; a[1] += x1; a[2] += x2;
    a[3] = fma(x0,x0,a[3]); a[4] = fma(x0,x1,a[4]); a[5] = fma(x0,x2,a[5]);
    a[6] = fma(x1,x1,a[6]); a[7] = fma(x1,x2,a[7]); a[8] = fma(x2,x2,a[8]);
    int v = idx[i]; if (v < 0) v = 0;
    atomicAdd(&cnt[v], 1);
  }
  #pragma unroll
  for (int j = 0; j < 9; j++){
    double v = a[j];
    for (int o = 32; o > 0; o >>= 1) v += __shfl_down(v, o, 64);
    if ((threadIdx.x & 63) == 0) unsafeAtomicAdd(&st0[j], v);
  }
}

// ---------------- K2: fold layer-0 GN into W0', b0' ----------------
__global__ void k_fold0(const double* __restrict__ st0, const float* __restrict__ W0,
                        const float* __restrict__ g0, const float* __restrict__ bt0,
                        float* __restrict__ w0p, float* __restrict__ b0p, int N){
  int c = threadIdx.x;  // 64 threads
  double sx0 = st0[0], sx1 = st0[1], sx2 = st0[2];
  double G00 = st0[3], G01 = st0[4], G02 = st0[5], G11 = st0[6], G12 = st0[7], G22 = st0[8];
  double s[2], q[2];
  int chans[2] = { c, c ^ 1 };
  #pragma unroll
  for (int t = 0; t < 2; t++){
    int ch = chans[t];
    double w0 = W0[ch*3+0], w1 = W0[ch*3+1], w2 = W0[ch*3+2];
    s[t] = w0*sx0 + w1*sx1 + w2*sx2;
    q[t] = w0*w0*G00 + w1*w1*G11 + w2*w2*G22 + 2.0*(w0*w1*G01 + w0*w2*G02 + w1*w2*G12);
  }
  double inv  = 1.0 / (2.0 * (double)N);
  double mean = (s[0] + s[1]) * inv;
  double var  = (q[0] + q[1]) * inv - mean*mean;
  double a    = (1.0 / sqrt(var + 1e-5)) * (double)g0[c];
  b0p[c] = (float)((double)bt0[c] - mean * a);
  w0p[c*3+0] = (float)((double)W0[c*3+0] * a);
  w0p[c*3+1] = (float)((double)W0[c*3+1] * a);
  w0p[c*3+2] = (float)((double)W0[c*3+2] * a);
}

// ---------------- K3: per-channel sum / sumsq of raw y1 = h0 @ W1^T ----------------
__global__ __launch_bounds__(128, 2)
void k_stats1(const float4* __restrict__ d4,
              const float* __restrict__ w0p, const float* __restrict__ b0p,
              const float* __restrict__ W1, double* __restrict__ st1,
              int N, int ntiles){
  __shared__ float lds[2][16][64][4];   // [wave][k/4][row][k%4]  (32 KB)
  int lane = threadIdx.x & 63;
  int wid  = threadIdx.x >> 6;
  // per-lane W1 row (raw)
  float w1r[64];
  #pragma unroll
  for (int k = 0; k < 64; k += 4){
    float4 t = *(const float4*)&W1[lane*64 + k];
    w1r[k] = t.x; w1r[k+1] = t.y; w1r[k+2] = t.z; w1r[k+3] = t.w;
  }
  double s0 = 0.0, s1 = 0.0;
  int gw = blockIdx.x*2 + wid, nw = gridDim.x*2;
  for (int t = gw; t < ntiles; t += nw){
    int rb = t * 64;
    int row = rb + lane;
    float4 d = (row < N) ? d4[row] : make_float4(0.f,0.f,0.f,0.f);
    waitlgkm();   // prior tile's reads done before overwrite
    #pragma unroll
    for (int cg = 0; cg < 16; cg++){
      float hv[4];
      #pragma unroll
      for (int u = 0; u < 4; u++){
        int c = cg*4 + u;
        float t0 = fmaf(w0p[c*3+2], d.z, fmaf(w0p[c*3+1], d.y, fmaf(w0p[c*3+0], d.x, b0p[c])));
        hv[u] = fmaxf(t0, 0.f);
      }
      float4 h4; h4.x = hv[0]; h4.y = hv[1]; h4.z = hv[2]; h4.w = hv[3];
      *(float4*)&lds[wid][cg][lane][0] = h4;
    }
    waitlgkm();
    int rmax = min(64, N - rb);
    for (int r = 0; r < rmax; r++){
      float a0 = 0.f, a1 = 0.f, a2 = 0.f, a3 = 0.f;
      #pragma unroll
      for (int kb = 0; kb < 16; kb++){
        float4 h = *(const float4*)&lds[wid][kb][r][0];
        a0 = fmaf(w1r[kb*4+0], h.x, a0);
        a1 = fmaf(w1r[kb*4+1], h.y, a1);
        a2 = fmaf(w1r[kb*4+2], h.z, a2);
        a3 = fmaf(w1r[kb*4+3], h.w, a3);
      }
      double y = (double)((a0 + a1) + (a2 + a3));
      s0 += y;
      s1 = fma(y, y, s1);
    }
  }
  unsafeAtomicAdd(&st1[lane],      s0);
  unsafeAtomicAdd(&st1[64 + lane], s1);
}

// ---------------- K4: fold layer-1 GN into W1', b1' ----------------
__global__ void k_fold1(const double* __restrict__ st1, const float* __restrict__ W1,
                        const float* __restrict__ g1, const float* __restrict__ bt1,
                        float* __restrict__ w1p, float* __restrict__ b1p, int N){
  int c = threadIdx.x;  // 64
  int p = c ^ 1;
  double inv  = 1.0 / (2.0 * (double)N);
  double mean = (st1[c] + st1[p]) * inv;
  double Ey2  = (st1[64+c] + st1[64+p]) * inv;
  double var  = Ey2 - mean*mean;
  double a    = (1.0 / sqrt(var + 1e-5)) * (double)g1[c];
  b1p[c] = (float)((double)bt1[c] - mean * a);
  for (int k = 0; k < 64; k++)
    w1p[c*64 + k] = (float)((double)W1[c*64 + k] * a);
}

// ---------------- K5: fused main pass + packed segment atomicMax ----------------
__global__ __launch_bounds__(128, 2)
void k_main(const float4* __restrict__ d4, const int* __restrict__ idx,
            const float* __restrict__ w0p, const float* __restrict__ b0p,
            const float* __restrict__ w1p, const float* __restrict__ b1p,
            const float* __restrict__ W2,  const float* __restrict__ b2,
            unsigned long long* __restrict__ seg, int N, int ntiles){
  __shared__ float lds[2][16][64][4];   // 32 KB
  __shared__ float scr[2][2][64];       // h1 broadcast, double-buffered by r parity
  int lane = threadIdx.x & 63;
  int wid  = threadIdx.x >> 6;
  float w1r[64], w2r[64];
  #pragma unroll
  for (int k = 0; k < 64; k += 4){
    float4 t1 = *(const float4*)&w1p[lane*64 + k];
    w1r[k] = t1.x; w1r[k+1] = t1.y; w1r[k+2] = t1.z; w1r[k+3] = t1.w;
    float4 t2 = *(const float4*)&W2[lane*64 + k];
    w2r[k] = t2.x; w2r[k+1] = t2.y; w2r[k+2] = t2.z; w2r[k+3] = t2.w;
  }
  float b1v = b1p[lane], b2v = b2[lane];
  int gw = blockIdx.x*2 + wid, nw = gridDim.x*2;
  for (int t = gw; t < ntiles; t += nw){
    int rb = t * 64;
    int row = rb + lane;
    float4 d = (row < N) ? d4[row] : make_float4(0.f,0.f,0.f,0.f);
    int myv = 0;
    if (row < N){ int v = idx[row]; myv = (v < 0) ? 0 : v; }
    waitlgkm();
    #pragma unroll
    for (int cg = 0; cg < 16; cg++){
      float hv[4];
      #pragma unroll
      for (int u = 0; u < 4; u++){
        int c = cg*4 + u;
        float t0 = fmaf(w0p[c*3+2], d.z, fmaf(w0p[c*3+1], d.y, fmaf(w0p[c*3+0], d.x, b0p[c])));
        hv[u] = fmaxf(t0, 0.f);
      }
      float4 h4; h4.x = hv[0]; h4.y = hv[1]; h4.z = hv[2]; h4.w = hv[3];
      *(float4*)&lds[wid][cg][lane][0] = h4;
    }
    waitlgkm();
    int rmax = min(64, N - rb);
    for (int r = 0; r < rmax; r++){
      int v = __builtin_amdgcn_readlane(myv, r);           // uniform vertex of row r
      float a0 = b1v, a1 = 0.f, a2 = 0.f, a3 = 0.f;
      #pragma unroll
      for (int kb = 0; kb < 16; kb++){
        float4 h = *(const float4*)&lds[wid][kb][r][0];
        a0 = fmaf(w1r[kb*4+0], h.x, a0);
        a1 = fmaf(w1r[kb*4+1], h.y, a1);
        a2 = fmaf(w1r[kb*4+2], h.z, a2);
        a3 = fmaf(w1r[kb*4+3], h.w, a3);
      }
      float h1 = fmaxf((a0 + a1) + (a2 + a3), 0.f);
      scr[wid][r & 1][lane] = h1;
      waitlgkm();
      float c0 = b2v, c1 = 0.f, c2 = 0.f, c3 = 0.f;
      #pragma unroll
      for (int kb = 0; kb < 16; kb++){
        float4 h = *(const float4*)&scr[wid][r & 1][kb*4];
        c0 = fmaf(w2r[kb*4+0], h.x, c0);
        c1 = fmaf(w2r[kb*4+1], h.y, c1);
        c2 = fmaf(w2r[kb*4+2], h.z, c2);
        c3 = fmaf(w2r[kb*4+3], h.w, c3);
      }
      float h2 = fmaxf((c0 + c1) + (c2 + c3), 0.f);
      unsigned int bits = __float_as_uint(h2) & 0x7fffffffu;   // canonicalize -0 -> +0
      unsigned long long packed =
          ((unsigned long long)bits << 32) | (unsigned long long)(unsigned int)(~(unsigned int)(rb + r));
      atomicMax(&seg[(size_t)v*64 + lane], packed);
    }
  }
}

// ---------------- K6: in-place unpack to final output ----------------
__global__ void k_out(const float4* __restrict__ d4, const int* __restrict__ cnt,
                      float* __restrict__ out, int N, int V){
  int lane = threadIdx.x & 63;
  int w = (int)((blockIdx.x*blockDim.x + threadIdx.x) >> 6);   // one wave per vertex
  if (w >= V) return;
  const unsigned long long* seg = (const unsigned long long*)out;
  unsigned long long p = seg[(size_t)w*64 + lane];
  int c = cnt[w];
  unsigned int bits = (unsigned int)(p >> 32);
  unsigned int rowu = ~(unsigned int)p;
  unsigned int nm1 = (unsigned int)(N - 1);
  if (rowu > nm1) rowu = nm1;
  float val  = __uint_as_float(bits);
  float bary = d4[rowu].w;
  bool few = (c < MIN_POINTS);
  float o0 = few ? 0.f : val;
  float o1 = few ? 0.f : bary;
  out[(size_t)w*128 + lane]      = o0;
  out[(size_t)w*128 + 64 + lane] = o1;
}

extern "C" void kernel_launch(void* const* d_in, const int* in_sizes, int n_in,
                              void* d_out, int out_size, void* d_ws, size_t ws_size,
                              hipStream_t stream) {
  const float4* d4  = (const float4*)d_in[0];
  const int*    idx = (const int*)d_in[1];
  const float*  W0  = (const float*)d_in[3];
  const float*  W1  = (const float*)d_in[4];
  const float*  W2  = (const float*)d_in[5];
  const float*  b2  = (const float*)d_in[6];
  const float*  g0  = (const float*)d_in[7];
  const float*  bt0 = (const float*)d_in[8];
  const float*  g1  = (const float*)d_in[9];
  const float*  bt1 = (const float*)d_in[10];

  int N = in_sizes[0] / 4;
  int V = out_size / 128;
  int ntiles = (N + 63) / 64;

  char* ws = (char*)d_ws;
  double* st0 = (double*)(ws + WS_ST0);
  double* st1 = (double*)(ws + WS_ST1);
  float*  w0p = (float*)(ws + WS_W0P);
  float*  b0p = (float*)(ws + WS_B0P);
  float*  w1p = (float*)(ws + WS_W1P);
  float*  b1p = (float*)(ws + WS_B1P);
  int*    cnt = (int*)(ws + WS_CNT);

  // zero stats + counts, and d_out (reused as packed segment buffer)
  hipMemsetAsync(d_ws, 0, WS_CNT + (size_t)V * sizeof(int), stream);
  hipMemsetAsync(d_out, 0, (size_t)out_size * sizeof(float), stream);

  k_stats0<<<1024, 256, 0, stream>>>(d4, idx, st0, cnt, N);
  k_fold0 <<<1, 64, 0, stream>>>(st0, W0, g0, bt0, w0p, b0p, N);
  k_stats1<<<1024, 128, 0, stream>>>(d4, w0p, b0p, W1, st1, N, ntiles);
  k_fold1 <<<1, 64, 0, stream>>>(st1, W1, g1, bt1, w1p, b1p, N);
  k_main  <<<1024, 128, 0, stream>>>(d4, idx, w0p, b0p, w1p, b1p, W2, b2,
                                     (unsigned long long*)d_out, N, ntiles);
  k_out   <<<(V + 3) / 4, 256, 0, stream>>>(d4, cnt, (float*)d_out, N, V);
}

// Round 2
// 671.641 us; speedup vs baseline: 1.5385x; 1.5385x over previous
//
#include <hip/hip_runtime.h>
#include <hip/hip_bf16.h>
#include <math.h>

#define MIN_POINTS 4

// ---- workspace layout (bytes) ----
#define WS_W0P   0         // 192 f32
#define WS_B0P   768       // 64 f32
#define WS_W1P   1024      // 4096 f32
#define WS_B1P   17408     // 64 f32
#define WS_CNT   17920     // V ints (400000 B)
#define WS_P0    417920    // partial0 [1024][16] f64 (131072 B)
#define WS_P1    548992    // part1 [1024][128] f64 (1048576 B)
#define NPART    1024

__device__ __forceinline__ void waitlgkm(){ asm volatile("s_waitcnt lgkmcnt(0)" ::: "memory"); }

// ---------------- K1: global stats of x (3-dim) + vertex counts ----------------
// Per-block LDS reduction + plain partial stores (NO contended f64 atomics).
__global__ void k_stats0(const float4* __restrict__ d4, const int* __restrict__ idx,
                         double* __restrict__ partial0, int* __restrict__ cnt, int N){
  __shared__ double red[4][16];
  int tid = blockIdx.x*blockDim.x + threadIdx.x;
  int stride = gridDim.x*blockDim.x;
  double a[9] = {0,0,0,0,0,0,0,0,0};
  for (int i = tid; i < N; i += stride){
    float4 d = d4[i];
    double x0 = d.x, x1 = d.y, x2 = d.z;
    a[0] += x0; a[1] += x1; a[2] += x2;
    a[3] = fma(x0,x0,a[3]); a[4] = fma(x0,x1,a[4]); a[5] = fma(x0,x2,a[5]);
    a[6] = fma(x1,x1,a[6]); a[7] = fma(x1,x2,a[7]); a[8] = fma(x2,x2,a[8]);
    int v = idx[i]; if (v < 0) v = 0;
    atomicAdd(&cnt[v], 1);   // scattered, fire-and-forget (diagnostic: see theory)
  }
  int lane = threadIdx.x & 63, wid = threadIdx.x >> 6;
  #pragma unroll
  for (int j = 0; j < 9; j++){
    double v = a[j];
    for (int o = 32; o > 0; o >>= 1) v += __shfl_down(v, o, 64);
    if (lane == 0) red[wid][j] = v;
  }
  __syncthreads();
  if (threadIdx.x < 9){
    double s = red[0][threadIdx.x] + red[1][threadIdx.x]
             + red[2][threadIdx.x] + red[3][threadIdx.x];
    partial0[blockIdx.x*16 + threadIdx.x] = s;
  }
}

// ---------------- K2: reduce partials + fold layer-0 GN into W0', b0' ----------------
__global__ void k_fold0(const double* __restrict__ partial0, const float* __restrict__ W0,
                        const float* __restrict__ g0, const float* __restrict__ bt0,
                        float* __restrict__ w0p, float* __restrict__ b0p, int N, int nparts){
  __shared__ double sred[16];
  int t = threadIdx.x, lane = t & 63, g = t >> 6;   // 1024 threads = 16 waves
  if (g < 9){
    double s = 0.0;
    for (int b = lane; b < nparts; b += 64) s += partial0[b*16 + g];
    for (int o = 32; o > 0; o >>= 1) s += __shfl_down(s, o, 64);
    if (lane == 0) sred[g] = s;
  }
  __syncthreads();
  if (t < 64){
    int c = t;
    double sx0 = sred[0], sx1 = sred[1], sx2 = sred[2];
    double G00 = sred[3], G01 = sred[4], G02 = sred[5], G11 = sred[6], G12 = sred[7], G22 = sred[8];
    double s[2], q[2];
    int chans[2] = { c, c ^ 1 };
    #pragma unroll
    for (int u = 0; u < 2; u++){
      int ch = chans[u];
      double w0 = W0[ch*3+0], w1 = W0[ch*3+1], w2 = W0[ch*3+2];
      s[u] = w0*sx0 + w1*sx1 + w2*sx2;
      q[u] = w0*w0*G00 + w1*w1*G11 + w2*w2*G22 + 2.0*(w0*w1*G01 + w0*w2*G02 + w1*w2*G12);
    }
    double inv  = 1.0 / (2.0 * (double)N);
    double mean = (s[0] + s[1]) * inv;
    double var  = (q[0] + q[1]) * inv - mean*mean;
    double aa   = (1.0 / sqrt(var + 1e-5)) * (double)g0[c];
    b0p[c] = (float)((double)bt0[c] - mean * aa);
    w0p[c*3+0] = (float)((double)W0[c*3+0] * aa);
    w0p[c*3+1] = (float)((double)W0[c*3+1] * aa);
    w0p[c*3+2] = (float)((double)W0[c*3+2] * aa);
  }
}

// ---------------- K3: per-channel sum / sumsq of raw y1 = h0 @ W1^T ----------------
__global__ __launch_bounds__(128, 2)
void k_stats1(const float4* __restrict__ d4,
              const float* __restrict__ w0p, const float* __restrict__ b0p,
              const float* __restrict__ W1, double* __restrict__ part1,
              int N, int ntiles){
  __shared__ float lds[2][16][64][4];   // [wave][k/4][row][k%4]  (32 KB)
  __shared__ double lds2[2][128];
  int lane = threadIdx.x & 63;
  int wid  = threadIdx.x >> 6;
  float w1r[64];
  #pragma unroll
  for (int k = 0; k < 64; k += 4){
    float4 t = *(const float4*)&W1[lane*64 + k];
    w1r[k] = t.x; w1r[k+1] = t.y; w1r[k+2] = t.z; w1r[k+3] = t.w;
  }
  double s0 = 0.0, s1 = 0.0;
  int gw = blockIdx.x*2 + wid, nw = gridDim.x*2;
  for (int t = gw; t < ntiles; t += nw){
    int rb = t * 64;
    int row = rb + lane;
    float4 d = (row < N) ? d4[row] : make_float4(0.f,0.f,0.f,0.f);
    waitlgkm();   // prior tile's reads done before overwrite
    #pragma unroll
    for (int cg = 0; cg < 16; cg++){
      float hv[4];
      #pragma unroll
      for (int u = 0; u < 4; u++){
        int c = cg*4 + u;
        float t0 = fmaf(w0p[c*3+2], d.z, fmaf(w0p[c*3+1], d.y, fmaf(w0p[c*3+0], d.x, b0p[c])));
        hv[u] = fmaxf(t0, 0.f);
      }
      float4 h4; h4.x = hv[0]; h4.y = hv[1]; h4.z = hv[2]; h4.w = hv[3];
      *(float4*)&lds[wid][cg][lane][0] = h4;
    }
    waitlgkm();
    int rmax = min(64, N - rb);
    for (int r = 0; r < rmax; r++){
      float a0 = 0.f, a1 = 0.f, a2 = 0.f, a3 = 0.f;
      #pragma unroll
      for (int kb = 0; kb < 16; kb++){
        float4 h = *(const float4*)&lds[wid][kb][r][0];
        a0 = fmaf(w1r[kb*4+0], h.x, a0);
        a1 = fmaf(w1r[kb*4+1], h.y, a1);
        a2 = fmaf(w1r[kb*4+2], h.z, a2);
        a3 = fmaf(w1r[kb*4+3], h.w, a3);
      }
      double y = (double)((a0 + a1) + (a2 + a3));
      s0 += y;
      s1 = fma(y, y, s1);
    }
  }
  // per-block combine + plain store (no contended atomics)
  lds2[wid][lane]      = s0;
  lds2[wid][64 + lane] = s1;
  __syncthreads();
  if (threadIdx.x < 128)
    part1[blockIdx.x*128 + threadIdx.x] = lds2[0][threadIdx.x] + lds2[1][threadIdx.x];
}

// ---------------- K4: reduce partials + fold layer-1 GN into W1', b1' ----------------
__global__ void k_fold1(const double* __restrict__ part1, const float* __restrict__ W1,
                        const float* __restrict__ g1, const float* __restrict__ bt1,
                        float* __restrict__ w1p, float* __restrict__ b1p, int N, int nparts){
  __shared__ double sst[128];
  int t = threadIdx.x;          // 1024 threads
  int s = t >> 3, j = t & 7;    // 128 slots x 8 reducers
  double acc = 0.0;
  for (int b = j; b < nparts; b += 8) acc += part1[b*128 + s];
  acc += __shfl_down(acc, 4, 8);
  acc += __shfl_down(acc, 2, 8);
  acc += __shfl_down(acc, 1, 8);
  if (j == 0) sst[s] = acc;
  __syncthreads();
  if (t < 64){
    int c = t, p = c ^ 1;
    double inv  = 1.0 / (2.0 * (double)N);
    double mean = (sst[c] + sst[p]) * inv;
    double Ey2  = (sst[64+c] + sst[64+p]) * inv;
    double var  = Ey2 - mean*mean;
    double a    = (1.0 / sqrt(var + 1e-5)) * (double)g1[c];
    b1p[c] = (float)((double)bt1[c] - mean * a);
    for (int k = 0; k < 64; k++)
      w1p[c*64 + k] = (float)((double)W1[c*64 + k] * a);
  }
}

// ---------------- K5: fused main pass + packed segment atomicMax ----------------
__global__ __launch_bounds__(128, 2)
void k_main(const float4* __restrict__ d4, const int* __restrict__ idx,
            const float* __restrict__ w0p, const float* __restrict__ b0p,
            const float* __restrict__ w1p, const float* __restrict__ b1p,
            const float* __restrict__ W2,  const float* __restrict__ b2,
            unsigned long long* __restrict__ seg, int N, int ntiles){
  __shared__ float lds[2][16][64][4];   // 32 KB
  __shared__ float scr[2][2][64];       // h1 broadcast, double-buffered by r parity
  int lane = threadIdx.x & 63;
  int wid  = threadIdx.x >> 6;
  float w1r[64], w2r[64];
  #pragma unroll
  for (int k = 0; k < 64; k += 4){
    float4 t1 = *(const float4*)&w1p[lane*64 + k];
    w1r[k] = t1.x; w1r[k+1] = t1.y; w1r[k+2] = t1.z; w1r[k+3] = t1.w;
    float4 t2 = *(const float4*)&W2[lane*64 + k];
    w2r[k] = t2.x; w2r[k+1] = t2.y; w2r[k+2] = t2.z; w2r[k+3] = t2.w;
  }
  float b1v = b1p[lane], b2v = b2[lane];
  int gw = blockIdx.x*2 + wid, nw = gridDim.x*2;
  for (int t = gw; t < ntiles; t += nw){
    int rb = t * 64;
    int row = rb + lane;
    float4 d = (row < N) ? d4[row] : make_float4(0.f,0.f,0.f,0.f);
    int myv = 0;
    if (row < N){ int v = idx[row]; myv = (v < 0) ? 0 : v; }
    waitlgkm();
    #pragma unroll
    for (int cg = 0; cg < 16; cg++){
      float hv[4];
      #pragma unroll
      for (int u = 0; u < 4; u++){
        int c = cg*4 + u;
        float t0 = fmaf(w0p[c*3+2], d.z, fmaf(w0p[c*3+1], d.y, fmaf(w0p[c*3+0], d.x, b0p[c])));
        hv[u] = fmaxf(t0, 0.f);
      }
      float4 h4; h4.x = hv[0]; h4.y = hv[1]; h4.z = hv[2]; h4.w = hv[3];
      *(float4*)&lds[wid][cg][lane][0] = h4;
    }
    waitlgkm();
    int rmax = min(64, N - rb);
    for (int r = 0; r < rmax; r++){
      int v = __builtin_amdgcn_readlane(myv, r);           // uniform vertex of row r
      float a0 = b1v, a1 = 0.f, a2 = 0.f, a3 = 0.f;
      #pragma unroll
      for (int kb = 0; kb < 16; kb++){
        float4 h = *(const float4*)&lds[wid][kb][r][0];
        a0 = fmaf(w1r[kb*4+0], h.x, a0);
        a1 = fmaf(w1r[kb*4+1], h.y, a1);
        a2 = fmaf(w1r[kb*4+2], h.z, a2);
        a3 = fmaf(w1r[kb*4+3], h.w, a3);
      }
      float h1 = fmaxf((a0 + a1) + (a2 + a3), 0.f);
      scr[wid][r & 1][lane] = h1;
      waitlgkm();
      float c0 = b2v, c1 = 0.f, c2 = 0.f, c3 = 0.f;
      #pragma unroll
      for (int kb = 0; kb < 16; kb++){
        float4 h = *(const float4*)&scr[wid][r & 1][kb*4];
        c0 = fmaf(w2r[kb*4+0], h.x, c0);
        c1 = fmaf(w2r[kb*4+1], h.y, c1);
        c2 = fmaf(w2r[kb*4+2], h.z, c2);
        c3 = fmaf(w2r[kb*4+3], h.w, c3);
      }
      float h2 = fmaxf((c0 + c1) + (c2 + c3), 0.f);
      unsigned int bits = __float_as_uint(h2) & 0x7fffffffu;   // canonicalize -0 -> +0
      unsigned long long packed =
          ((unsigned long long)bits << 32) | (unsigned long long)(unsigned int)(~(unsigned int)(rb + r));
      atomicMax(&seg[(size_t)v*64 + lane], packed);
    }
  }
}

// ---------------- K6: in-place unpack to final output ----------------
__global__ void k_out(const float4* __restrict__ d4, const int* __restrict__ cnt,
                      float* __restrict__ out, int N, int V){
  int lane = threadIdx.x & 63;
  int w = (int)((blockIdx.x*blockDim.x + threadIdx.x) >> 6);   // one wave per vertex
  if (w >= V) return;
  const unsigned long long* seg = (const unsigned long long*)out;
  unsigned long long p = seg[(size_t)w*64 + lane];
  int c = cnt[w];
  unsigned int bits = (unsigned int)(p >> 32);
  unsigned int rowu = ~(unsigned int)p;
  unsigned int nm1 = (unsigned int)(N - 1);
  if (rowu > nm1) rowu = nm1;
  float val  = __uint_as_float(bits);
  float bary = d4[rowu].w;
  bool few = (c < MIN_POINTS);
  float o0 = few ? 0.f : val;
  float o1 = few ? 0.f : bary;
  out[(size_t)w*128 + lane]      = o0;
  out[(size_t)w*128 + 64 + lane] = o1;
}

extern "C" void kernel_launch(void* const* d_in, const int* in_sizes, int n_in,
                              void* d_out, int out_size, void* d_ws, size_t ws_size,
                              hipStream_t stream) {
  const float4* d4  = (const float4*)d_in[0];
  const int*    idx = (const int*)d_in[1];
  const float*  W0  = (const float*)d_in[3];
  const float*  W1  = (const float*)d_in[4];
  const float*  W2  = (const float*)d_in[5];
  const float*  b2  = (const float*)d_in[6];
  const float*  g0  = (const float*)d_in[7];
  const float*  bt0 = (const float*)d_in[8];
  const float*  g1  = (const float*)d_in[9];
  const float*  bt1 = (const float*)d_in[10];

  int N = in_sizes[0] / 4;
  int V = out_size / 128;
  int ntiles = (N + 63) / 64;

  char* ws = (char*)d_ws;
  float*  w0p = (float*)(ws + WS_W0P);
  float*  b0p = (float*)(ws + WS_B0P);
  float*  w1p = (float*)(ws + WS_W1P);
  float*  b1p = (float*)(ws + WS_B1P);
  int*    cnt = (int*)(ws + WS_CNT);
  double* p0  = (double*)(ws + WS_P0);
  double* p1  = (double*)(ws + WS_P1);

  // zero counts and d_out (reused as packed segment buffer); partials are fully overwritten
  hipMemsetAsync(cnt, 0, (size_t)V * sizeof(int), stream);
  hipMemsetAsync(d_out, 0, (size_t)out_size * sizeof(float), stream);

  k_stats0<<<NPART, 256, 0, stream>>>(d4, idx, p0, cnt, N);
  k_fold0 <<<1, 1024, 0, stream>>>(p0, W0, g0, bt0, w0p, b0p, N, NPART);
  k_stats1<<<NPART, 128, 0, stream>>>(d4, w0p, b0p, W1, p1, N, ntiles);
  k_fold1 <<<1, 1024, 0, stream>>>(p1, W1, g1, bt1, w1p, b1p, N, NPART);
  k_main  <<<NPART, 128, 0, stream>>>(d4, idx, w0p, b0p, w1p, b1p, W2, b2,
                                      (unsigned long long*)d_out, N, ntiles);
  k_out   <<<(V + 3) / 4, 256, 0, stream>>>(d4, cnt, (float*)d_out, N, V);
}